// Round 10
// baseline (282.732 us; speedup 1.0000x reference)
//
#include <hip/hip_runtime.h>
#include <stdint.h>

typedef unsigned long long u64;
typedef uint32_t u32;

#define BB  32
#define CC  256
#define HH  56
#define WW  56
#define OHH 28
#define OWW 28
#define NPIX (BB*OHH*OWW)   // 25088
#define PACKBLKS 3136       // 802816/256
#define FGRID (BB*OHH)      // 896 fused blocks

// ---------------- Kernel 0: pack sign(x+beta1)+avgpool (blocks 0..3135)
//                  + weight prep/alpha/barrier-zero (blocks 3136..3647) --------------
__global__ __launch_bounds__(256) void rrb_prep_pack(const float* __restrict__ x,
                                                     const float* __restrict__ rsb1,
                                                     const float* __restrict__ w1,
                                                     const float* __restrict__ w2,
                                                     u32* __restrict__ xb, float* __restrict__ pool,
                                                     u32* __restrict__ wp1, u32* __restrict__ wp2,
                                                     float* __restrict__ alpha1, float* __restrict__ alpha2,
                                                     int* __restrict__ bar) {
    if (blockIdx.x >= PACKBLKS) {
        __shared__ float red[256];
        int pb = blockIdx.x - PACKBLKS;     // 0..511
        int co = pb & 255;
        int t = threadIdx.x;                // ci
        int wid = t >> 6, lane = t & 63;
        if (pb == 0 && t == 0) *bar = 0;
        float asum = 0.f;
        if (pb < 256) {
            const float* wr = w1 + (size_t)co * 2304 + (size_t)t * 9;
            float v[9];
            #pragma unroll
            for (int k = 0; k < 9; ++k) { v[k] = wr[k]; asum += fabsf(v[k]); }
            #pragma unroll
            for (int k = 0; k < 9; ++k) {
                u64 m = __ballot(v[k] > 0.f);
                if (lane == 0)
                    *(u64*)&wp1[((size_t)co * 9 + k) * 8 + 2 * wid] = m;
            }
        } else {
            float v = w2[co * 256 + t];
            asum = fabsf(v);
            u64 m = __ballot(v > 0.f);
            if (lane == 0) *(u64*)&wp2[co * 8 + 2 * wid] = m;
        }
        red[t] = asum; __syncthreads();
        for (int st = 128; st > 0; st >>= 1) {
            if (t < st) red[t] += red[t + st];
            __syncthreads();
        }
        if (t == 0) {
            if (pb < 256) alpha1[co] = red[0] / 2304.f;
            else          alpha2[co] = red[0] / 256.f;
        }
        return;
    }
    // ---- pack path: thread = (j-word, n, oh, ow, s-subslice) ----
    int i = blockIdx.x * 256 + threadIdx.x;   // 802816
    int s  = i & 3;
    int i2 = i >> 2;
    int ow = i2 % OWW;
    int i3 = i2 / OWW;
    int oh = i3 % OHH;
    int i4 = i3 / OHH;
    int n  = i4 & 31;
    int j  = i4 >> 5;
    int c0 = 32 * j + 8 * s;
    const float* base = x + (((size_t)(n * CC + c0) * HH + 2 * oh) * WW + 2 * ow);

    float2 a0[8], a1[8];
    #pragma unroll
    for (int cc = 0; cc < 8; ++cc) {
        const float* p = base + (size_t)cc * (HH * WW);
        a0[cc] = *(const float2*)p;
        a1[cc] = *(const float2*)(p + WW);
    }
    float4 b0 = *(const float4*)&rsb1[c0];
    float4 b1 = *(const float4*)&rsb1[c0 + 4];

    u32 w00 = 0, w01 = 0, w10 = 0, w11 = 0;
    float pv[8];
    #pragma unroll
    for (int cc = 0; cc < 8; ++cc) {
        float b = (cc < 4) ? ((const float*)&b0)[cc] : ((const float*)&b1)[cc - 4];
        w00 |= (u32)(a0[cc].x + b > 0.f) << cc;
        w01 |= (u32)(a0[cc].y + b > 0.f) << cc;
        w10 |= (u32)(a1[cc].x + b > 0.f) << cc;
        w11 |= (u32)(a1[cc].y + b > 0.f) << cc;
        pv[cc] = (a0[cc].x + a0[cc].y + a1[cc].x + a1[cc].y) * 0.25f;
    }
    w00 <<= 8 * s; w01 <<= 8 * s; w10 <<= 8 * s; w11 <<= 8 * s;
    w00 |= __shfl_xor(w00, 1); w00 |= __shfl_xor(w00, 2);
    w01 |= __shfl_xor(w01, 1); w01 |= __shfl_xor(w01, 2);
    w10 |= __shfl_xor(w10, 1); w10 |= __shfl_xor(w10, 2);
    w11 |= __shfl_xor(w11, 1); w11 |= __shfl_xor(w11, 2);

    float* pp = pool + ((size_t)(n * OHH + oh) * OWW + ow) * CC + c0;
    *(float4*)&pp[0] = make_float4(pv[0], pv[1], pv[2], pv[3]);
    *(float4*)&pp[4] = make_float4(pv[4], pv[5], pv[6], pv[7]);

    u32* xo = xb + (((size_t)(n * HH + 2 * oh) * WW + 2 * ow) * 8) + j;
    u32 wsel = (s == 0) ? w00 : (s == 1) ? w01 : (s == 2) ? w10 : w11;
    int off = (s == 0) ? 0 : (s == 1) ? 8 : (s == 2) ? WW * 8 : WW * 8 + 8;
    xo[off] = wsel;
}

// ---- fence-free device spin barrier (monotonic counter, RELAXED ops only) ----
__device__ __forceinline__ void gbar(int* cnt, int target) {
    __syncthreads();
    if (threadIdx.x == 0) {
        __hip_atomic_fetch_add(cnt, 1, __ATOMIC_RELAXED, __HIP_MEMORY_SCOPE_AGENT);
        int guard = 0;
        while (__hip_atomic_load(cnt, __ATOMIC_RELAXED, __HIP_MEMORY_SCOPE_AGENT) < target) {
            __builtin_amdgcn_s_sleep(16);
            if (++guard > (1 << 20)) break;   // bounded bail-out: fail, don't hang
        }
    }
    __syncthreads();
}

// ---- BN finalize from exact integer stats ----
__device__ __forceinline__ void bn_fold_v(long long sv, u64 qv, float al_, float g_, float be_,
                                          float& a, float& b) {
    const double N = (double)NPIX;
    double s = (double)sv;
    double q = (double)qv;
    double mS = s / N;
    double vS = q / N - mS * mS;
    double al = (double)al_;
    double scale = (double)g_ / sqrt(al * al * vS + 1e-5);
    a = (float)(al * scale);
    b = (float)((double)be_ - al * mS * scale);
}

#define AST(p, v)  __hip_atomic_store((p), (v), __ATOMIC_RELAXED, __HIP_MEMORY_SCOPE_AGENT)
#define ALD(p)     __hip_atomic_load((p), __ATOMIC_RELAXED, __HIP_MEMORY_SCOPE_AGENT)

// ---------------- Persistent fused kernel ----------------
// conv1 -> partials -> bar -> reduce(bn1) -> bar -> out1+conv2partials -> bar
//       -> reduce(bn2) -> bar -> y.  No atomic RMWs except barrier arrivals.
__global__ __launch_bounds__(256, 4) void rrb_fused(const u32* __restrict__ xb,
                                                    const u32* __restrict__ wp1,
                                                    const u32* __restrict__ wp2,
                                                    const float* __restrict__ pool,
                                                    int* __restrict__ P1s, u32* __restrict__ P1q,
                                                    int* __restrict__ P2s, u32* __restrict__ P2q,
                                                    u32* __restrict__ A1, u32* __restrict__ B1,
                                                    u32* __restrict__ A2, u32* __restrict__ B2,
                                                    const float* __restrict__ alpha1,
                                                    const float* __restrict__ bn1g, const float* __restrict__ bn1b,
                                                    const float* __restrict__ alpha2,
                                                    const float* __restrict__ bn2g, const float* __restrict__ bn2b,
                                                    const float* __restrict__ pg, const float* __restrict__ pz,
                                                    const float* __restrict__ ps, const float* __restrict__ rsb2,
                                                    float* __restrict__ y, int* __restrict__ bar) {
    __shared__ char shraw[256 * 29 * 4 + OWW * 8 * 4];   // 30592 B
    u32*       xs   = (u32*)shraw;                  // phase A: 5376 B (dead after A)
    float*     tb   = (float*)shraw;                // phase C transpose (aliases xs)
    long long* redS = (long long*)shraw;            // reduce scratch 2048 B (aliases xs)
    long long* redQ = (long long*)(shraw + 2048);   // reduce scratch 2048 B
    u32*       bits = (u32*)(shraw + 256 * 29 * 4); // sign bits, live B->C

    int blk = blockIdx.x;
    int n = blk / OHH, oh = blk - n * OHH;
    int c = threadIdx.x;
    int wid = c >> 6, lane = c & 63;

    // -------- Phase A: binary conv1 (3x3,s2,p1) -> packed S in regs + partials --------
    int r0 = 2 * oh - 1;
    for (int i = c; i < 3 * WW * 8; i += 256) {
        int row = i / (WW * 8);
        int ih = r0 + row;
        xs[i] = (ih >= 0) ? xb[((size_t)(n * HH + ih) * WW) * 8 + (i - row * WW * 8)] : 0u;
    }
    u32 svp[14];    // 28 x i16 conv1 sums, packed
    {
        u32 wreg[72];
        const u32* wsrc = wp1 + (size_t)c * 72;
        #pragma unroll
        for (int i = 0; i < 72; ++i) wreg[i] = wsrc[i];
        __syncthreads();
        bool oh0 = (oh == 0);
        int bsum = 0; long long bsq = 0;
        #pragma unroll
        for (int ow = 0; ow < OWW; ++ow) {
            int S = 0;
            #pragma unroll
            for (int kh = 0; kh < 3; ++kh) {
                bool vkh = !(kh == 0 && oh0);
                #pragma unroll
                for (int kw = 0; kw < 3; ++kw) {
                    int iw = 2 * ow + kw - 1;
                    bool ok = vkh && (iw >= 0);
                    int iwc = iw < 0 ? 0 : iw;
                    const u32* xp = &xs[(kh * WW + iwc) * 8];
                    int p = 0;
                    #pragma unroll
                    for (int j = 0; j < 8; ++j) p += __popc(xp[j] ^ wreg[(kh * 3 + kw) * 8 + j]);
                    S += ok ? (256 - 2 * p) : 0;
                }
            }
            if ((ow & 1) == 0) svp[ow >> 1] = (u32)(S & 0xffff);
            else               svp[ow >> 1] |= (u32)(S & 0xffff) << 16;
            bsum += S;
            bsq += (long long)S * S;
        }
        AST(&P1s[blk * 256 + c], bsum);        // coalesced coherent-point stores, no RMW
        AST(&P1q[blk * 256 + c], (u32)bsq);    // bsq <= 28*256^2 < 2^32
        asm volatile("s_waitcnt vmcnt(0)" ::: "memory");
    }

    gbar(bar, FGRID);

    // -------- Reduce 1: block r<256 owns channel r -> A1,B1 --------
    if (blk < 256) {
        int r = blk;
        long long aS = 0, aQ = 0;
        for (int k = c; k < FGRID; k += 256) {
            aS += (long long)(int)ALD(&P1s[k * 256 + r]);
            aQ += (long long)(u64)ALD(&P1q[k * 256 + r]);
        }
        redS[c] = aS; redQ[c] = aQ; __syncthreads();
        for (int st = 128; st > 0; st >>= 1) {
            if (c < st) { redS[c] += redS[c + st]; redQ[c] += redQ[c + st]; }
            __syncthreads();
        }
        if (c == 0) {
            float a, b;
            bn_fold_v(redS[0], (u64)redQ[0], alpha1[r], bn1g[r], bn1b[r], a, b);
            AST(&A1[r], __float_as_uint(a));
            AST(&B1[r], __float_as_uint(b));
            asm volatile("s_waitcnt vmcnt(0)" ::: "memory");
        }
    }

    gbar(bar, 2 * FGRID);

    // -------- Phase B: out1 = rprelu(bn1(S)+pool) in regs; sign2 bits; conv2 partials ----
    float ov[OWW];
    u32 wr2[8];
    {
        float a1 = __uint_as_float(ALD(&A1[c]));
        float b1 = __uint_as_float(ALD(&B1[c]));
        float g = pg[c], z = pz[c], sl = ps[c], b2 = rsb2[c];
        const float* pp = pool + ((size_t)(n * OHH + oh) * OWW) * CC + c;
        #pragma unroll
        for (int k = 0; k < OWW; ++k) {
            int S = (k & 1) ? (((int)svp[k >> 1]) >> 16)
                            : (((int)(svp[k >> 1] << 16)) >> 16);
            float v = a1 * (float)S + b1 + pp[k * CC];
            float xsv = v - g;
            float o = (xsv > 0.f ? xsv : sl * xsv) + z;
            ov[k] = o;
            u64 m = __ballot(o + b2 > 0.f);
            if (lane == 0) *(u64*)&bits[k * 8 + 2 * wid] = m;
        }
        const u32* wsv = wp2 + (size_t)c * 8;
        #pragma unroll
        for (int j = 0; j < 8; ++j) wr2[j] = wsv[j];
        __syncthreads();
        int bsum = 0; long long bsq = 0;
        #pragma unroll
        for (int k = 0; k < OWW; ++k) {
            int p = 0;
            #pragma unroll
            for (int j = 0; j < 8; ++j) p += __popc(bits[k * 8 + j] ^ wr2[j]);
            int S = 256 - 2 * p;
            bsum += S;
            bsq += (long long)S * S;
        }
        AST(&P2s[blk * 256 + c], bsum);
        AST(&P2q[blk * 256 + c], (u32)bsq);
        asm volatile("s_waitcnt vmcnt(0)" ::: "memory");
    }

    gbar(bar, 3 * FGRID);

    // -------- Reduce 2 -> A2,B2 (redS/redQ alias xs region; bits untouched) --------
    if (blk < 256) {
        int r = blk;
        long long aS = 0, aQ = 0;
        for (int k = c; k < FGRID; k += 256) {
            aS += (long long)(int)ALD(&P2s[k * 256 + r]);
            aQ += (long long)(u64)ALD(&P2q[k * 256 + r]);
        }
        redS[c] = aS; redQ[c] = aQ; __syncthreads();
        for (int st = 128; st > 0; st >>= 1) {
            if (c < st) { redS[c] += redS[c + st]; redQ[c] += redQ[c + st]; }
            __syncthreads();
        }
        if (c == 0) {
            float a, b;
            bn_fold_v(redS[0], (u64)redQ[0], alpha2[r], bn2g[r], bn2b[r], a, b);
            AST(&A2[r], __float_as_uint(a));
            AST(&B2[r], __float_as_uint(b));
            asm volatile("s_waitcnt vmcnt(0)" ::: "memory");
        }
    }

    gbar(bar, 4 * FGRID);

    // -------- Phase C: S2 from LDS bits, y = bn2(S2)+out1, transpose, concat --------
    {
        float a2  = __uint_as_float(ALD(&A2[c]));
        float b2f = __uint_as_float(ALD(&B2[c]));
        float sv2[OWW];
        #pragma unroll
        for (int ow = 0; ow < OWW; ++ow) {
            int p = 0;
            #pragma unroll
            for (int j = 0; j < 8; ++j) p += __popc(bits[ow * 8 + j] ^ wr2[j]);
            sv2[ow] = a2 * (float)(256 - 2 * p) + b2f + ov[ow];
        }
        __syncthreads();   // bits fully read before tb overwrites shraw? (bits beyond tb区) safe; sync for xs alias
        #pragma unroll
        for (int ow = 0; ow < OWW; ++ow) tb[c * 29 + ow] = sv2[ow];
        __syncthreads();
        #pragma unroll
        for (int it = 0; it < 7; ++it) {
            int idx = it * 256 + c;        // 0..1791 = 256 rows x 7 float4
            int cp = idx / 7, qq = idx - cp * 7;
            const float* lp = &tb[cp * 29 + 4 * qq];
            float4 v = make_float4(lp[0], lp[1], lp[2], lp[3]);
            float* dst = y + ((size_t)(n * 2 * CC + cp) * OHH + oh) * OWW + 4 * qq;
            *(float4*)dst = v;
            *(float4*)(dst + (size_t)CC * OHH * OWW) = v;
        }
    }
}

extern "C" void kernel_launch(void* const* d_in, const int* in_sizes, int n_in,
                              void* d_out, int out_size, void* d_ws, size_t ws_size,
                              hipStream_t stream) {
    const float* x    = (const float*)d_in[0];
    const float* rsb1 = (const float*)d_in[1];
    const float* w1   = (const float*)d_in[2];
    const float* bn1g = (const float*)d_in[3];
    const float* bn1b = (const float*)d_in[4];
    const float* rsb2 = (const float*)d_in[5];
    const float* w2   = (const float*)d_in[6];
    const float* bn2g = (const float*)d_in[7];
    const float* bn2b = (const float*)d_in[8];
    const float* pg   = (const float*)d_in[9];
    const float* pz   = (const float*)d_in[10];
    const float* ps   = (const float*)d_in[11];
    float* y = (float*)d_out;

    char* ws = (char*)d_ws;
    if (ws_size < 32665600) return;

    u32*   wp1    = (u32*)(ws + 0);          // 73728 B
    u32*   wp2    = (u32*)(ws + 73728);      // 8192 B
    float* alpha1 = (float*)(ws + 81920);
    float* alpha2 = (float*)(ws + 82944);
    int*   bar    = (int*)(ws + 84992);
    u32*   A1     = (u32*)(ws + 86016);      // 1024 B each
    u32*   B1     = (u32*)(ws + 87040);
    u32*   A2     = (u32*)(ws + 88064);
    u32*   B2     = (u32*)(ws + 89088);
    u32*   xb   = (u32*)(ws + 94208);        // 3,211,264 B   [n][h][w][8]
    float* pool = (float*)(ws + 3305472);    // 25,690,112 B  [pix][256]
    int*   P1s  = (int*)(ws + 28995584);     // 917,504 B     [block][channel]
    u32*   P1q  = (u32*)(ws + 29913088);     // 917,504 B
    int*   P2s  = (int*)(ws + 30830592);     // 917,504 B
    u32*   P2q  = (u32*)(ws + 31748096);     // 917,504 B -> end 32,665,600

    rrb_prep_pack<<<PACKBLKS + 512, 256, 0, stream>>>(x, rsb1, w1, w2, xb, pool,
                                                      wp1, wp2, alpha1, alpha2, bar);
    rrb_fused<<<FGRID, 256, 0, stream>>>(xb, wp1, wp2, pool,
                                         P1s, P1q, P2s, P2q, A1, B1, A2, B2,
                                         alpha1, bn1g, bn1b, alpha2, bn2g, bn2b,
                                         pg, pz, ps, rsb2, y, bar);
}

// Round 11
// 205.289 us; speedup vs baseline: 1.3772x; 1.3772x over previous
//
#include <hip/hip_runtime.h>
#include <stdint.h>

typedef unsigned long long u64;
typedef uint32_t u32;

#define BB  32
#define CC  256
#define HH  56
#define WW  56
#define OHH 28
#define OWW 28
#define NPIX (BB*OHH*OWW)   // 25088
#define PACKBLKS 3136       // 802816/256

// ---------------- Kernel 0: pack sign(x+beta1)+avgpool (blocks 0..3135)
//                  + weight prep/alpha (blocks 3136..3647) ----------------
__global__ __launch_bounds__(256) void rrb_prep_pack(const float* __restrict__ x,
                                                     const float* __restrict__ rsb1,
                                                     const float* __restrict__ w1,
                                                     const float* __restrict__ w2,
                                                     u32* __restrict__ xb, float* __restrict__ pool,
                                                     u32* __restrict__ wp1, u32* __restrict__ wp2,
                                                     float* __restrict__ alpha1, float* __restrict__ alpha2) {
    if (blockIdx.x >= PACKBLKS) {
        __shared__ float red[256];
        int pb = blockIdx.x - PACKBLKS;     // 0..511
        int co = pb & 255;
        int t = threadIdx.x;                // ci
        int wid = t >> 6, lane = t & 63;
        float asum = 0.f;
        if (pb < 256) {
            const float* wr = w1 + (size_t)co * 2304 + (size_t)t * 9;
            float v[9];
            #pragma unroll
            for (int k = 0; k < 9; ++k) { v[k] = wr[k]; asum += fabsf(v[k]); }
            #pragma unroll
            for (int k = 0; k < 9; ++k) {
                u64 m = __ballot(v[k] > 0.f);
                if (lane == 0)
                    *(u64*)&wp1[((size_t)co * 9 + k) * 8 + 2 * wid] = m;
            }
        } else {
            float v = w2[co * 256 + t];
            asum = fabsf(v);
            u64 m = __ballot(v > 0.f);
            if (lane == 0) *(u64*)&wp2[co * 8 + 2 * wid] = m;
        }
        red[t] = asum; __syncthreads();
        for (int st = 128; st > 0; st >>= 1) {
            if (t < st) red[t] += red[t + st];
            __syncthreads();
        }
        if (t == 0) {
            if (pb < 256) alpha1[co] = red[0] / 2304.f;
            else          alpha2[co] = red[0] / 256.f;
        }
        return;
    }
    // ---- pack path: thread = (j-word, n, oh, ow, s-subslice) ----
    int i = blockIdx.x * 256 + threadIdx.x;   // 802816
    int s  = i & 3;
    int i2 = i >> 2;
    int ow = i2 % OWW;
    int i3 = i2 / OWW;
    int oh = i3 % OHH;
    int i4 = i3 / OHH;
    int n  = i4 & 31;
    int j  = i4 >> 5;
    int c0 = 32 * j + 8 * s;
    const float* base = x + (((size_t)(n * CC + c0) * HH + 2 * oh) * WW + 2 * ow);

    float2 a0[8], a1[8];
    #pragma unroll
    for (int cc = 0; cc < 8; ++cc) {
        const float* p = base + (size_t)cc * (HH * WW);
        a0[cc] = *(const float2*)p;
        a1[cc] = *(const float2*)(p + WW);
    }
    float4 b0 = *(const float4*)&rsb1[c0];
    float4 b1 = *(const float4*)&rsb1[c0 + 4];

    u32 w00 = 0, w01 = 0, w10 = 0, w11 = 0;
    float pv[8];
    #pragma unroll
    for (int cc = 0; cc < 8; ++cc) {
        float b = (cc < 4) ? ((const float*)&b0)[cc] : ((const float*)&b1)[cc - 4];
        w00 |= (u32)(a0[cc].x + b > 0.f) << cc;
        w01 |= (u32)(a0[cc].y + b > 0.f) << cc;
        w10 |= (u32)(a1[cc].x + b > 0.f) << cc;
        w11 |= (u32)(a1[cc].y + b > 0.f) << cc;
        pv[cc] = (a0[cc].x + a0[cc].y + a1[cc].x + a1[cc].y) * 0.25f;
    }
    w00 <<= 8 * s; w01 <<= 8 * s; w10 <<= 8 * s; w11 <<= 8 * s;
    w00 |= __shfl_xor(w00, 1); w00 |= __shfl_xor(w00, 2);
    w01 |= __shfl_xor(w01, 1); w01 |= __shfl_xor(w01, 2);
    w10 |= __shfl_xor(w10, 1); w10 |= __shfl_xor(w10, 2);
    w11 |= __shfl_xor(w11, 1); w11 |= __shfl_xor(w11, 2);

    float* pp = pool + ((size_t)(n * OHH + oh) * OWW + ow) * CC + c0;
    *(float4*)&pp[0] = make_float4(pv[0], pv[1], pv[2], pv[3]);
    *(float4*)&pp[4] = make_float4(pv[4], pv[5], pv[6], pv[7]);

    u32* xo = xb + (((size_t)(n * HH + 2 * oh) * WW + 2 * ow) * 8) + j;
    u32 wsel = (s == 0) ? w00 : (s == 1) ? w01 : (s == 2) ? w10 : w11;
    int off = (s == 0) ? 0 : (s == 1) ? 8 : (s == 2) ? WW * 8 : WW * 8 + 8;
    xo[off] = wsel;
}

// ---------------- Kernel 1: binary conv1 (3x3,s2,p1) -> S1 + per-block partial stats ------
__global__ __launch_bounds__(256) void rrb_conv1(const u32* __restrict__ xb,
                                                 const u32* __restrict__ wp1,
                                                 short* __restrict__ S1,
                                                 int* __restrict__ P1s, int* __restrict__ P1q) {
    __shared__ u32 xs[3 * WW * 8];   // 5.25 KB
    int blk = blockIdx.x;
    int n = blk / OHH, oh = blk - n * OHH;
    int t = threadIdx.x;             // co
    int r0 = 2 * oh - 1;
    for (int i = t; i < 3 * WW * 8; i += 256) {
        int row = i / (WW * 8);
        int ih = r0 + row;
        xs[i] = (ih >= 0) ? xb[((size_t)(n * HH + ih) * WW) * 8 + (i - row * WW * 8)] : 0u;
    }
    u32 wreg[72];
    {
        const u32* wsrc = wp1 + (size_t)t * 72;
        #pragma unroll
        for (int i = 0; i < 72; ++i) wreg[i] = wsrc[i];
    }
    __syncthreads();
    bool oh0 = (oh == 0);
    int bsum = 0, bsq = 0;           // bsq <= 28*256^2 = 1.83M, int32 exact
    short* outp = S1 + ((size_t)(n * OHH + oh) * OWW) * CC + t;
    for (int ow = 0; ow < OWW; ++ow) {
        int S = 0;
        #pragma unroll
        for (int kh = 0; kh < 3; ++kh) {
            bool vkh = !(kh == 0 && oh0);
            #pragma unroll
            for (int kw = 0; kw < 3; ++kw) {
                int iw = 2 * ow + kw - 1;
                bool ok = vkh && (iw >= 0);
                int iwc = iw < 0 ? 0 : iw;
                const u32* xp = &xs[(kh * WW + iwc) * 8];
                int p = 0;
                #pragma unroll
                for (int j = 0; j < 8; ++j) p += __popc(xp[j] ^ wreg[(kh * 3 + kw) * 8 + j]);
                S += ok ? (256 - 2 * p) : 0;
            }
        }
        outp[ow * CC] = (short)S;
        bsum += S;
        bsq += S * S;
    }
    P1s[blk * CC + t] = bsum;        // plain cached coalesced stores; kernel boundary = sync
    P1q[blk * CC + t] = bsq;
}

// ---------------- Reduce kernel: column-sum partials (int32 exact) -> BN A,B --------------
// Grid 8 blocks; block m owns channels [32m,32m+32). Thread t=(ks*32+co), ks=t>>5.
__global__ __launch_bounds__(256) void rrb_reduce(const int* __restrict__ Ps,
                                                  const int* __restrict__ Pq,
                                                  int nrows,
                                                  const float* __restrict__ alpha,
                                                  const float* __restrict__ gamma,
                                                  const float* __restrict__ beta,
                                                  float* __restrict__ A, float* __restrict__ Bv) {
    __shared__ int rS[256], rQ[256];
    int t = threadIdx.x;
    int ks = t >> 5, co = t & 31;
    int ch = blockIdx.x * 32 + co;
    int aS = 0, aQ = 0;              // max totals 1.64e9 < 2^31: int32 exact
    for (int i = ks; i < nrows; i += 8) {
        aS += Ps[i * CC + ch];
        aQ += Pq[i * CC + ch];
    }
    rS[t] = aS; rQ[t] = aQ; __syncthreads();
    if (t < 128) { rS[t] += rS[t + 128]; rQ[t] += rQ[t + 128]; } __syncthreads();
    if (t < 64)  { rS[t] += rS[t + 64];  rQ[t] += rQ[t + 64];  } __syncthreads();
    if (t < 32)  {
        int sS = rS[t] + rS[t + 32];
        int sQ = rQ[t] + rQ[t + 32];
        const double N = (double)NPIX;
        double s = (double)sS;
        double q = (double)sQ;
        double mS = s / N;
        double vS = q / N - mS * mS;
        double al = (double)alpha[ch];
        double scale = (double)gamma[ch] / sqrt(al * al * vS + 1e-5);
        A[ch]  = (float)(al * scale);
        Bv[ch] = (float)((double)beta[ch] - al * mS * scale);
    }
}

// ---------------- Kernel 2: out1 = rprelu(bn1+pool) in-place + conv2 partial stats --------
// Block = (n, oh, ow-half of 14).
__global__ __launch_bounds__(256) void rrb_out1c2(const short* __restrict__ S1,
                                                  float* __restrict__ pool,
                                                  const float* __restrict__ A1, const float* __restrict__ B1,
                                                  const float* __restrict__ pg, const float* __restrict__ pz,
                                                  const float* __restrict__ ps, const float* __restrict__ rsb2,
                                                  const u32* __restrict__ wp2,
                                                  int* __restrict__ P2s, int* __restrict__ P2q) {
    __shared__ u32 bits[14 * 8];     // 448 B of sign bits
    int blk = blockIdx.x;
    int half = blk & 1;
    int rest = blk >> 1;
    int n = rest / OHH, oh = rest - n * OHH;
    int owlo = half * 14;
    int c = threadIdx.x;
    int wid = c >> 6, lane = c & 63;
    float a = A1[c], b = B1[c];
    float g = pg[c], z = pz[c], s = ps[c], b2 = rsb2[c];
    size_t pixbase = ((size_t)(n * OHH + oh) * OWW + owlo);
    const short* sp = S1 + pixbase * CC + c;
    float* pp = pool + pixbase * CC + c;
    float sv[14], pv[14];
    #pragma unroll
    for (int k = 0; k < 14; ++k) sv[k] = (float)sp[k * CC];
    #pragma unroll
    for (int k = 0; k < 14; ++k) pv[k] = pp[k * CC];
    #pragma unroll
    for (int k = 0; k < 14; ++k) {
        float v = a * sv[k] + b + pv[k];
        float xsv = v - g;
        float o = (xsv > 0.f ? xsv : s * xsv) + z;
        pp[k * CC] = o;
        u64 m = __ballot(o + b2 > 0.f);
        if (lane == 0) *(u64*)&bits[k * 8 + 2 * wid] = m;
    }
    u32 wr[8];
    {
        const u32* wsv = wp2 + (size_t)c * 8;
        #pragma unroll
        for (int j = 0; j < 8; ++j) wr[j] = wsv[j];
    }
    __syncthreads();
    int bsum = 0, bsq = 0;           // bsq <= 14*65536 = 917k, int32 exact
    #pragma unroll
    for (int k = 0; k < 14; ++k) {
        int p = 0;
        #pragma unroll
        for (int j = 0; j < 8; ++j) p += __popc(bits[k * 8 + j] ^ wr[j]);
        int S = 256 - 2 * p;
        bsum += S;
        bsq += S * S;
    }
    P2s[blk * CC + c] = bsum;
    P2q[blk * CC + c] = bsq;
}

// ---------------- Kernel 3: recompute conv2 from out1, y = bn2 + out1, concat -------------
// Block (n, oh). Re-ballots the SAME sign bits as out1c2 (same f32 values -> bit-identical).
__global__ __launch_bounds__(256) void rrb_final(const float* __restrict__ out1,
                                                 const float* __restrict__ A2, const float* __restrict__ B2,
                                                 const float* __restrict__ rsb2,
                                                 const u32* __restrict__ wp2,
                                                 float* __restrict__ y) {
    __shared__ u32 bits[OWW * 8];    // 896 B
    __shared__ float lds[256 * 29];  // 29.7 KB transpose buffer (pad 29)
    int blk = blockIdx.x;
    int n = blk / OHH, oh = blk - n * OHH;
    int c = threadIdx.x;
    int wid = c >> 6, lane = c & 63;
    float a = A2[c], b = B2[c];
    float b2 = rsb2[c];
    size_t pixbase = ((size_t)(n * OHH + oh) * OWW);
    const float* op = out1 + pixbase * CC + c;
    float ov[OWW];
    #pragma unroll
    for (int ow = 0; ow < OWW; ++ow) ov[ow] = op[ow * CC];
    #pragma unroll
    for (int ow = 0; ow < OWW; ++ow) {
        u64 m = __ballot(ov[ow] + b2 > 0.f);
        if (lane == 0) *(u64*)&bits[ow * 8 + 2 * wid] = m;
    }
    u32 wr[8];
    {
        const u32* wsv = wp2 + (size_t)c * 8;
        #pragma unroll
        for (int j = 0; j < 8; ++j) wr[j] = wsv[j];
    }
    __syncthreads();
    #pragma unroll
    for (int ow = 0; ow < OWW; ++ow) {
        int p = 0;
        #pragma unroll
        for (int j = 0; j < 8; ++j) p += __popc(bits[ow * 8 + j] ^ wr[j]);
        int S = 256 - 2 * p;
        lds[c * 29 + ow] = a * (float)S + b + ov[ow];
    }
    __syncthreads();
    #pragma unroll
    for (int it = 0; it < 7; ++it) {
        int idx = it * 256 + c;        // 0..1791 = 256 rows x 7 float4
        int cp = idx / 7, qq = idx - cp * 7;
        const float* lp = &lds[cp * 29 + 4 * qq];
        float4 v = make_float4(lp[0], lp[1], lp[2], lp[3]);
        float* dst = y + ((size_t)(n * 2 * CC + cp) * OHH + oh) * OWW + 4 * qq;
        *(float4*)dst = v;
        *(float4*)(dst + (size_t)CC * OHH * OWW) = v;
    }
}

extern "C" void kernel_launch(void* const* d_in, const int* in_sizes, int n_in,
                              void* d_out, int out_size, void* d_ws, size_t ws_size,
                              hipStream_t stream) {
    const float* x    = (const float*)d_in[0];
    const float* rsb1 = (const float*)d_in[1];
    const float* w1   = (const float*)d_in[2];
    const float* bn1g = (const float*)d_in[3];
    const float* bn1b = (const float*)d_in[4];
    const float* rsb2 = (const float*)d_in[5];
    const float* w2   = (const float*)d_in[6];
    const float* bn2g = (const float*)d_in[7];
    const float* bn2b = (const float*)d_in[8];
    const float* pg   = (const float*)d_in[9];
    const float* pz   = (const float*)d_in[10];
    const float* ps   = (const float*)d_in[11];
    float* y = (float*)d_out;

    char* ws = (char*)d_ws;
    if (ws_size < 47345664) return;

    u32*   wp1    = (u32*)(ws + 0);          // 73728 B
    u32*   wp2    = (u32*)(ws + 73728);      // 8192 B
    float* alpha1 = (float*)(ws + 81920);    // 1024 B
    float* alpha2 = (float*)(ws + 82944);    // 1024 B
    float* A1     = (float*)(ws + 83968);
    float* B1     = (float*)(ws + 84992);
    float* A2     = (float*)(ws + 86016);
    float* B2     = (float*)(ws + 87040);
    u32*   xb   = (u32*)(ws + 94208);        // 3,211,264 B   [n][h][w][8]
    float* pool = (float*)(ws + 3305472);    // 25,690,112 B  [pix][256] (becomes out1)
    short* S1   = (short*)(ws + 28995584);   // 12,845,056 B  [pix][256]
    int*   P1s  = (int*)(ws + 41840640);     // 917,504 B     [896][256]
    int*   P1q  = (int*)(ws + 42758144);     // 917,504 B
    int*   P2s  = (int*)(ws + 43675648);     // 1,835,008 B   [1792][256]
    int*   P2q  = (int*)(ws + 45510656);     // 1,835,008 B -> end 47,345,664

    rrb_prep_pack<<<PACKBLKS + 512, 256, 0, stream>>>(x, rsb1, w1, w2, xb, pool,
                                                      wp1, wp2, alpha1, alpha2);
    rrb_conv1<<<BB * OHH, 256, 0, stream>>>(xb, wp1, S1, P1s, P1q);
    rrb_reduce<<<8, 256, 0, stream>>>(P1s, P1q, BB * OHH, alpha1, bn1g, bn1b, A1, B1);
    rrb_out1c2<<<BB * OHH * 2, 256, 0, stream>>>(S1, pool, A1, B1, pg, pz, ps, rsb2,
                                                 wp2, P2s, P2q);
    rrb_reduce<<<8, 256, 0, stream>>>(P2s, P2q, BB * OHH * 2, alpha2, bn2g, bn2b, A2, B2);
    rrb_final<<<BB * OHH, 256, 0, stream>>>(pool, A2, B2, rsb2, wp2, y);
}

// Round 12
// 166.812 us; speedup vs baseline: 1.6949x; 1.2307x over previous
//
#include <hip/hip_runtime.h>
#include <stdint.h>

typedef unsigned long long u64;
typedef uint32_t u32;

#define BB  32
#define CC  256
#define HH  56
#define WW  56
#define OHH 28
#define OWW 28
#define NPIX (BB*OHH*OWW)   // 25088
#define PACKBLKS 3136       // 802816/256

// ---------------- Kernel 0: pack sign(x+beta1)+avgpool (blocks 0..3135)
//                  + weight prep/alpha (blocks 3136..3647) ----------------
__global__ __launch_bounds__(256) void rrb_prep_pack(const float* __restrict__ x,
                                                     const float* __restrict__ rsb1,
                                                     const float* __restrict__ w1,
                                                     const float* __restrict__ w2,
                                                     u32* __restrict__ xb, float* __restrict__ pool,
                                                     u32* __restrict__ wp1, u32* __restrict__ wp2,
                                                     float* __restrict__ alpha1, float* __restrict__ alpha2) {
    if (blockIdx.x >= PACKBLKS) {
        __shared__ float red[256];
        int pb = blockIdx.x - PACKBLKS;     // 0..511
        int co = pb & 255;
        int t = threadIdx.x;                // ci
        int wid = t >> 6, lane = t & 63;
        float asum = 0.f;
        if (pb < 256) {
            const float* wr = w1 + (size_t)co * 2304 + (size_t)t * 9;
            float v[9];
            #pragma unroll
            for (int k = 0; k < 9; ++k) { v[k] = wr[k]; asum += fabsf(v[k]); }
            #pragma unroll
            for (int k = 0; k < 9; ++k) {
                u64 m = __ballot(v[k] > 0.f);
                if (lane == 0)
                    *(u64*)&wp1[((size_t)co * 9 + k) * 8 + 2 * wid] = m;
            }
        } else {
            float v = w2[co * 256 + t];
            asum = fabsf(v);
            u64 m = __ballot(v > 0.f);
            if (lane == 0) *(u64*)&wp2[co * 8 + 2 * wid] = m;
        }
        red[t] = asum; __syncthreads();
        for (int st = 128; st > 0; st >>= 1) {
            if (t < st) red[t] += red[t + st];
            __syncthreads();
        }
        if (t == 0) {
            if (pb < 256) alpha1[co] = red[0] / 2304.f;
            else          alpha2[co] = red[0] / 256.f;
        }
        return;
    }
    // ---- pack path: thread = (j-word, n, oh, ow, s-subslice) ----
    int i = blockIdx.x * 256 + threadIdx.x;   // 802816
    int s  = i & 3;
    int i2 = i >> 2;
    int ow = i2 % OWW;
    int i3 = i2 / OWW;
    int oh = i3 % OHH;
    int i4 = i3 / OHH;
    int n  = i4 & 31;
    int j  = i4 >> 5;
    int c0 = 32 * j + 8 * s;
    const float* base = x + (((size_t)(n * CC + c0) * HH + 2 * oh) * WW + 2 * ow);

    float2 a0[8], a1[8];
    #pragma unroll
    for (int cc = 0; cc < 8; ++cc) {
        const float* p = base + (size_t)cc * (HH * WW);
        a0[cc] = *(const float2*)p;
        a1[cc] = *(const float2*)(p + WW);
    }
    float4 b0 = *(const float4*)&rsb1[c0];
    float4 b1 = *(const float4*)&rsb1[c0 + 4];

    u32 w00 = 0, w01 = 0, w10 = 0, w11 = 0;
    float pv[8];
    #pragma unroll
    for (int cc = 0; cc < 8; ++cc) {
        float b = (cc < 4) ? ((const float*)&b0)[cc] : ((const float*)&b1)[cc - 4];
        w00 |= (u32)(a0[cc].x + b > 0.f) << cc;
        w01 |= (u32)(a0[cc].y + b > 0.f) << cc;
        w10 |= (u32)(a1[cc].x + b > 0.f) << cc;
        w11 |= (u32)(a1[cc].y + b > 0.f) << cc;
        pv[cc] = (a0[cc].x + a0[cc].y + a1[cc].x + a1[cc].y) * 0.25f;
    }
    w00 <<= 8 * s; w01 <<= 8 * s; w10 <<= 8 * s; w11 <<= 8 * s;
    w00 |= __shfl_xor(w00, 1); w00 |= __shfl_xor(w00, 2);
    w01 |= __shfl_xor(w01, 1); w01 |= __shfl_xor(w01, 2);
    w10 |= __shfl_xor(w10, 1); w10 |= __shfl_xor(w10, 2);
    w11 |= __shfl_xor(w11, 1); w11 |= __shfl_xor(w11, 2);

    float* pp = pool + ((size_t)(n * OHH + oh) * OWW + ow) * CC + c0;
    *(float4*)&pp[0] = make_float4(pv[0], pv[1], pv[2], pv[3]);
    *(float4*)&pp[4] = make_float4(pv[4], pv[5], pv[6], pv[7]);

    u32* xo = xb + (((size_t)(n * HH + 2 * oh) * WW + 2 * ow) * 8) + j;
    u32 wsel = (s == 0) ? w00 : (s == 1) ? w01 : (s == 2) ? w10 : w11;
    int off = (s == 0) ? 0 : (s == 1) ? 8 : (s == 2) ? WW * 8 : WW * 8 + 8;
    xo[off] = wsel;
}

// ---------------- Kernel 1: binary conv1 (3x3,s2,p1), SPLIT-K over input-word halves ------
// 512 threads: c = t&255 (co), h = t>>8 (words 4h..4h+3). Each half popcounts 4 words/tap
// into Q_h; LDS combine; h=0 waves emit S = 256*V - 2(Q0+Q1) (V = valid taps) + partials.
// Integer-exact == previous formulation. wreg halves 72->36 -> VGPR/occupancy fix.
__global__ __launch_bounds__(512) void rrb_conv1(const u32* __restrict__ xb,
                                                 const u32* __restrict__ wp1,
                                                 short* __restrict__ S1,
                                                 int* __restrict__ P1s, int* __restrict__ P1q) {
    __shared__ u32 xs[3 * WW * 8];          // 5376 B
    __shared__ ushort qh[OWW][2][256];      // 28672 B
    int blk = blockIdx.x;
    int n = blk / OHH, oh = blk - n * OHH;
    int t = threadIdx.x;
    int c = t & 255;
    int h = t >> 8;
    int r0 = 2 * oh - 1;
    for (int i = t; i < 3 * WW * 8; i += 512) {
        int row = i / (WW * 8);
        int ih = r0 + row;
        xs[i] = (ih >= 0) ? xb[((size_t)(n * HH + ih) * WW) * 8 + (i - row * WW * 8)] : 0u;
    }
    u32 wreg[36];
    {
        const u32* wsrc = wp1 + (size_t)c * 72 + 4 * h;
        #pragma unroll
        for (int k = 0; k < 9; ++k) {
            wreg[4 * k + 0] = wsrc[8 * k + 0];
            wreg[4 * k + 1] = wsrc[8 * k + 1];
            wreg[4 * k + 2] = wsrc[8 * k + 2];
            wreg[4 * k + 3] = wsrc[8 * k + 3];
        }
    }
    __syncthreads();
    bool oh0 = (oh == 0);
    #pragma unroll
    for (int ow = 0; ow < OWW; ++ow) {
        int Q = 0;
        #pragma unroll
        for (int kh = 0; kh < 3; ++kh) {
            bool vkh = !(kh == 0 && oh0);
            #pragma unroll
            for (int kw = 0; kw < 3; ++kw) {
                int iw = 2 * ow + kw - 1;
                bool ok = vkh && (iw >= 0);
                int iwc = iw < 0 ? 0 : iw;
                const u32* xp = &xs[(kh * WW + iwc) * 8 + 4 * h];
                int p = 0;
                #pragma unroll
                for (int j = 0; j < 4; ++j) p += __popc(xp[j] ^ wreg[(kh * 3 + kw) * 4 + j]);
                Q += ok ? p : 0;
            }
        }
        qh[ow][h][c] = (ushort)Q;
    }
    __syncthreads();
    if (h == 0) {
        int rv = oh0 ? 2 : 3;
        int bsum = 0, bsq = 0;       // bsq <= 28*256^2, int32 exact
        short* outp = S1 + ((size_t)(n * OHH + oh) * OWW) * CC + c;
        #pragma unroll
        for (int ow = 0; ow < OWW; ++ow) {
            int V = rv * (ow == 0 ? 2 : 3);
            int S = 256 * V - 2 * ((int)qh[ow][0][c] + (int)qh[ow][1][c]);
            outp[ow * CC] = (short)S;
            bsum += S;
            bsq += S * S;
        }
        P1s[blk * CC + c] = bsum;
        P1q[blk * CC + c] = bsq;
    }
}

// ---------------- Reduce kernel: column-sum partials (int32 exact) -> BN A,B --------------
__global__ __launch_bounds__(256) void rrb_reduce(const int* __restrict__ Ps,
                                                  const int* __restrict__ Pq,
                                                  int nrows,
                                                  const float* __restrict__ alpha,
                                                  const float* __restrict__ gamma,
                                                  const float* __restrict__ beta,
                                                  float* __restrict__ A, float* __restrict__ Bv) {
    __shared__ int rS[256], rQ[256];
    int t = threadIdx.x;
    int ks = t >> 5, co = t & 31;
    int ch = blockIdx.x * 32 + co;
    int aS = 0, aQ = 0;              // max totals 1.64e9 < 2^31: int32 exact
    for (int i = ks; i < nrows; i += 8) {
        aS += Ps[i * CC + ch];
        aQ += Pq[i * CC + ch];
    }
    rS[t] = aS; rQ[t] = aQ; __syncthreads();
    if (t < 128) { rS[t] += rS[t + 128]; rQ[t] += rQ[t + 128]; } __syncthreads();
    if (t < 64)  { rS[t] += rS[t + 64];  rQ[t] += rQ[t + 64];  } __syncthreads();
    if (t < 32)  {
        int sS = rS[t] + rS[t + 32];
        int sQ = rQ[t] + rQ[t + 32];
        const double N = (double)NPIX;
        double s = (double)sS;
        double q = (double)sQ;
        double mS = s / N;
        double vS = q / N - mS * mS;
        double al = (double)alpha[ch];
        double scale = (double)gamma[ch] / sqrt(al * al * vS + 1e-5);
        A[ch]  = (float)(al * scale);
        Bv[ch] = (float)((double)beta[ch] - al * mS * scale);
    }
}

// ---------------- Kernel 2: out1 = rprelu(bn1+pool) in-place + conv2 partial stats --------
__global__ __launch_bounds__(256) void rrb_out1c2(const short* __restrict__ S1,
                                                  float* __restrict__ pool,
                                                  const float* __restrict__ A1, const float* __restrict__ B1,
                                                  const float* __restrict__ pg, const float* __restrict__ pz,
                                                  const float* __restrict__ ps, const float* __restrict__ rsb2,
                                                  const u32* __restrict__ wp2,
                                                  int* __restrict__ P2s, int* __restrict__ P2q) {
    __shared__ u32 bits[14 * 8];     // 448 B of sign bits
    int blk = blockIdx.x;
    int half = blk & 1;
    int rest = blk >> 1;
    int n = rest / OHH, oh = rest - n * OHH;
    int owlo = half * 14;
    int c = threadIdx.x;
    int wid = c >> 6, lane = c & 63;
    float a = A1[c], b = B1[c];
    float g = pg[c], z = pz[c], s = ps[c], b2 = rsb2[c];
    size_t pixbase = ((size_t)(n * OHH + oh) * OWW + owlo);
    const short* sp = S1 + pixbase * CC + c;
    float* pp = pool + pixbase * CC + c;
    float sv[14], pv[14];
    #pragma unroll
    for (int k = 0; k < 14; ++k) sv[k] = (float)sp[k * CC];
    #pragma unroll
    for (int k = 0; k < 14; ++k) pv[k] = pp[k * CC];
    #pragma unroll
    for (int k = 0; k < 14; ++k) {
        float v = a * sv[k] + b + pv[k];
        float xsv = v - g;
        float o = (xsv > 0.f ? xsv : s * xsv) + z;
        pp[k * CC] = o;
        u64 m = __ballot(o + b2 > 0.f);
        if (lane == 0) *(u64*)&bits[k * 8 + 2 * wid] = m;
    }
    u32 wr[8];
    {
        const u32* wsv = wp2 + (size_t)c * 8;
        #pragma unroll
        for (int j = 0; j < 8; ++j) wr[j] = wsv[j];
    }
    __syncthreads();
    int bsum = 0, bsq = 0;           // bsq <= 14*65536, int32 exact
    #pragma unroll
    for (int k = 0; k < 14; ++k) {
        int p = 0;
        #pragma unroll
        for (int j = 0; j < 8; ++j) p += __popc(bits[k * 8 + j] ^ wr[j]);
        int S = 256 - 2 * p;
        bsum += S;
        bsq += S * S;
    }
    P2s[blk * CC + c] = bsum;
    P2q[blk * CC + c] = bsq;
}

// ---------------- Kernel 3: recompute conv2 from out1, y = bn2 + out1, concat -------------
__global__ __launch_bounds__(256) void rrb_final(const float* __restrict__ out1,
                                                 const float* __restrict__ A2, const float* __restrict__ B2,
                                                 const float* __restrict__ rsb2,
                                                 const u32* __restrict__ wp2,
                                                 float* __restrict__ y) {
    __shared__ u32 bits[OWW * 8];    // 896 B
    __shared__ float lds[256 * 29];  // 29.7 KB transpose buffer (pad 29)
    int blk = blockIdx.x;
    int n = blk / OHH, oh = blk - n * OHH;
    int c = threadIdx.x;
    int wid = c >> 6, lane = c & 63;
    float a = A2[c], b = B2[c];
    float b2 = rsb2[c];
    size_t pixbase = ((size_t)(n * OHH + oh) * OWW);
    const float* op = out1 + pixbase * CC + c;
    float ov[OWW];
    #pragma unroll
    for (int ow = 0; ow < OWW; ++ow) ov[ow] = op[ow * CC];
    #pragma unroll
    for (int ow = 0; ow < OWW; ++ow) {
        u64 m = __ballot(ov[ow] + b2 > 0.f);
        if (lane == 0) *(u64*)&bits[ow * 8 + 2 * wid] = m;
    }
    u32 wr[8];
    {
        const u32* wsv = wp2 + (size_t)c * 8;
        #pragma unroll
        for (int j = 0; j < 8; ++j) wr[j] = wsv[j];
    }
    __syncthreads();
    #pragma unroll
    for (int ow = 0; ow < OWW; ++ow) {
        int p = 0;
        #pragma unroll
        for (int j = 0; j < 8; ++j) p += __popc(bits[ow * 8 + j] ^ wr[j]);
        int S = 256 - 2 * p;
        lds[c * 29 + ow] = a * (float)S + b + ov[ow];
    }
    __syncthreads();
    #pragma unroll
    for (int it = 0; it < 7; ++it) {
        int idx = it * 256 + c;        // 0..1791 = 256 rows x 7 float4
        int cp = idx / 7, qq = idx - cp * 7;
        const float* lp = &lds[cp * 29 + 4 * qq];
        float4 v = make_float4(lp[0], lp[1], lp[2], lp[3]);
        float* dst = y + ((size_t)(n * 2 * CC + cp) * OHH + oh) * OWW + 4 * qq;
        *(float4*)dst = v;
        *(float4*)(dst + (size_t)CC * OHH * OWW) = v;
    }
}

extern "C" void kernel_launch(void* const* d_in, const int* in_sizes, int n_in,
                              void* d_out, int out_size, void* d_ws, size_t ws_size,
                              hipStream_t stream) {
    const float* x    = (const float*)d_in[0];
    const float* rsb1 = (const float*)d_in[1];
    const float* w1   = (const float*)d_in[2];
    const float* bn1g = (const float*)d_in[3];
    const float* bn1b = (const float*)d_in[4];
    const float* rsb2 = (const float*)d_in[5];
    const float* w2   = (const float*)d_in[6];
    const float* bn2g = (const float*)d_in[7];
    const float* bn2b = (const float*)d_in[8];
    const float* pg   = (const float*)d_in[9];
    const float* pz   = (const float*)d_in[10];
    const float* ps   = (const float*)d_in[11];
    float* y = (float*)d_out;

    char* ws = (char*)d_ws;
    if (ws_size < 47345664) return;

    u32*   wp1    = (u32*)(ws + 0);          // 73728 B
    u32*   wp2    = (u32*)(ws + 73728);      // 8192 B
    float* alpha1 = (float*)(ws + 81920);
    float* alpha2 = (float*)(ws + 82944);
    float* A1     = (float*)(ws + 83968);
    float* B1     = (float*)(ws + 84992);
    float* A2     = (float*)(ws + 86016);
    float* B2     = (float*)(ws + 87040);
    u32*   xb   = (u32*)(ws + 94208);        // 3,211,264 B   [n][h][w][8]
    float* pool = (float*)(ws + 3305472);    // 25,690,112 B  [pix][256] (becomes out1)
    short* S1   = (short*)(ws + 28995584);   // 12,845,056 B  [pix][256]
    int*   P1s  = (int*)(ws + 41840640);     // 917,504 B     [896][256]
    int*   P1q  = (int*)(ws + 42758144);     // 917,504 B
    int*   P2s  = (int*)(ws + 43675648);     // 1,835,008 B   [1792][256]
    int*   P2q  = (int*)(ws + 45510656);     // 1,835,008 B -> end 47,345,664

    rrb_prep_pack<<<PACKBLKS + 512, 256, 0, stream>>>(x, rsb1, w1, w2, xb, pool,
                                                      wp1, wp2, alpha1, alpha2);
    rrb_conv1<<<BB * OHH, 512, 0, stream>>>(xb, wp1, S1, P1s, P1q);
    rrb_reduce<<<8, 256, 0, stream>>>(P1s, P1q, BB * OHH, alpha1, bn1g, bn1b, A1, B1);
    rrb_out1c2<<<BB * OHH * 2, 256, 0, stream>>>(S1, pool, A1, B1, pg, pz, ps, rsb2,
                                                 wp2, P2s, P2q);
    rrb_reduce<<<8, 256, 0, stream>>>(P2s, P2q, BB * OHH * 2, alpha2, bn2g, bn2b, A2, B2);
    rrb_final<<<BB * OHH, 256, 0, stream>>>(pool, A2, B2, rsb2, wp2, y);
}

// Round 13
// 147.804 us; speedup vs baseline: 1.9129x; 1.1286x over previous
//
#include <hip/hip_runtime.h>
#include <stdint.h>

typedef unsigned long long u64;
typedef uint32_t u32;

#define BB  32
#define CC  256
#define HH  56
#define WW  56
#define OHH 28
#define OWW 28
#define NPIX (BB*OHH*OWW)   // 25088

// ---------------- Kernel 0: weight prep (alpha + bit-pack) + stats zeroing ----------------
__global__ __launch_bounds__(256) void rrb_prep_w(const float* __restrict__ w1,
                                                  const float* __restrict__ w2,
                                                  u32* __restrict__ wp1, u32* __restrict__ wp2,
                                                  float* __restrict__ alpha1, float* __restrict__ alpha2,
                                                  u32* __restrict__ stats_zero) {
    __shared__ float red[256];
    int co = blockIdx.x & 255;
    int t = threadIdx.x;            // ci
    int wid = t >> 6, lane = t & 63;
    if (blockIdx.x == 0) {          // zero 6144 B of stats (replaces hipMemsetAsync)
        #pragma unroll
        for (int k = 0; k < 6; ++k) stats_zero[k * 256 + t] = 0u;
    }
    float asum = 0.f;
    if (blockIdx.x < 256) {
        const float* wr = w1 + (size_t)co * 2304 + (size_t)t * 9;
        float v[9];
        #pragma unroll
        for (int k = 0; k < 9; ++k) { v[k] = wr[k]; asum += fabsf(v[k]); }
        #pragma unroll
        for (int k = 0; k < 9; ++k) {
            u64 m = __ballot(v[k] > 0.f);
            if (lane == 0)
                *(u64*)&wp1[((size_t)co * 9 + k) * 8 + 2 * wid] = m;
        }
    } else {
        float v = w2[co * 256 + t];
        asum = fabsf(v);
        u64 m = __ballot(v > 0.f);
        if (lane == 0) *(u64*)&wp2[co * 8 + 2 * wid] = m;
    }
    red[t] = asum; __syncthreads();
    for (int st = 128; st > 0; st >>= 1) {
        if (t < st) red[t] += red[t + st];
        __syncthreads();
    }
    if (t == 0) {
        if (blockIdx.x < 256) alpha1[co] = red[0] / 2304.f;
        else                  alpha2[co] = red[0] / 256.f;
    }
}

// ---------------- Kernel 1: pack sign(x+beta1) bits + 2x2 avgpool ----------------
// Thread = (j-word, n, oh, ow, s) with s = 8-channel sub-slice (s = i&3 fastest).
__global__ __launch_bounds__(256) void rrb_pack_x(const float* __restrict__ x,
                                                  const float* __restrict__ rsb1,
                                                  u32* __restrict__ xb, float* __restrict__ pool) {
    int i = blockIdx.x * 256 + threadIdx.x;   // 4*28*28*32*8 = 802816
    int s  = i & 3;
    int i2 = i >> 2;
    int ow = i2 % OWW;
    int i3 = i2 / OWW;
    int oh = i3 % OHH;
    int i4 = i3 / OHH;
    int n  = i4 & 31;
    int j  = i4 >> 5;
    int c0 = 32 * j + 8 * s;
    const float* base = x + (((size_t)(n * CC + c0) * HH + 2 * oh) * WW + 2 * ow);

    float2 a0[8], a1[8];
    #pragma unroll
    for (int cc = 0; cc < 8; ++cc) {
        const float* p = base + (size_t)cc * (HH * WW);
        a0[cc] = *(const float2*)p;
        a1[cc] = *(const float2*)(p + WW);
    }
    float4 b0 = *(const float4*)&rsb1[c0];
    float4 b1 = *(const float4*)&rsb1[c0 + 4];

    u32 w00 = 0, w01 = 0, w10 = 0, w11 = 0;
    float pv[8];
    #pragma unroll
    for (int cc = 0; cc < 8; ++cc) {
        float b = (cc < 4) ? ((const float*)&b0)[cc] : ((const float*)&b1)[cc - 4];
        w00 |= (u32)(a0[cc].x + b > 0.f) << cc;
        w01 |= (u32)(a0[cc].y + b > 0.f) << cc;
        w10 |= (u32)(a1[cc].x + b > 0.f) << cc;
        w11 |= (u32)(a1[cc].y + b > 0.f) << cc;
        pv[cc] = (a0[cc].x + a0[cc].y + a1[cc].x + a1[cc].y) * 0.25f;
    }
    w00 <<= 8 * s; w01 <<= 8 * s; w10 <<= 8 * s; w11 <<= 8 * s;
    w00 |= __shfl_xor(w00, 1); w00 |= __shfl_xor(w00, 2);
    w01 |= __shfl_xor(w01, 1); w01 |= __shfl_xor(w01, 2);
    w10 |= __shfl_xor(w10, 1); w10 |= __shfl_xor(w10, 2);
    w11 |= __shfl_xor(w11, 1); w11 |= __shfl_xor(w11, 2);

    float* pp = pool + ((size_t)(n * OHH + oh) * OWW + ow) * CC + c0;
    *(float4*)&pp[0] = make_float4(pv[0], pv[1], pv[2], pv[3]);
    *(float4*)&pp[4] = make_float4(pv[4], pv[5], pv[6], pv[7]);

    u32* xo = xb + (((size_t)(n * HH + 2 * oh) * WW + 2 * ow) * 8) + j;
    u32 wsel = (s == 0) ? w00 : (s == 1) ? w01 : (s == 2) ? w10 : w11;
    int off = (s == 0) ? 0 : (s == 1) ? 8 : (s == 2) ? WW * 8 : WW * 8 + 8;
    xo[off] = wsel;
}

// ---------------- Kernel 2: binary conv1 (3x3,s2,p1), SPLIT-K + bn1 atomic stats ----------
// 512 threads: c = t&255 (co), h = t>>8 (input words 4h..4h+3). Each half popcounts into
// qh; h=0 combines S = 256*V - 2(Q0+Q1), writes S1, atomically accumulates bn1 stats.
__global__ __launch_bounds__(512) void rrb_conv1(const u32* __restrict__ xb,
                                                 const u32* __restrict__ wp1,
                                                 short* __restrict__ S1,
                                                 int* __restrict__ s_sum, u64* __restrict__ s_sq) {
    __shared__ u32 xs[3 * WW * 8];          // 5376 B
    __shared__ ushort qh[OWW][2][256];      // 28672 B
    int blk = blockIdx.x;
    int n = blk / OHH, oh = blk - n * OHH;
    int t = threadIdx.x;
    int c = t & 255;
    int h = t >> 8;
    int r0 = 2 * oh - 1;
    for (int i = t; i < 3 * WW * 8; i += 512) {
        int row = i / (WW * 8);
        int ih = r0 + row;
        xs[i] = (ih >= 0) ? xb[((size_t)(n * HH + ih) * WW) * 8 + (i - row * WW * 8)] : 0u;
    }
    u32 wreg[36];
    {
        const u32* wsrc = wp1 + (size_t)c * 72 + 4 * h;
        #pragma unroll
        for (int k = 0; k < 9; ++k) {
            wreg[4 * k + 0] = wsrc[8 * k + 0];
            wreg[4 * k + 1] = wsrc[8 * k + 1];
            wreg[4 * k + 2] = wsrc[8 * k + 2];
            wreg[4 * k + 3] = wsrc[8 * k + 3];
        }
    }
    __syncthreads();
    bool oh0 = (oh == 0);
    #pragma unroll
    for (int ow = 0; ow < OWW; ++ow) {
        int Q = 0;
        #pragma unroll
        for (int kh = 0; kh < 3; ++kh) {
            bool vkh = !(kh == 0 && oh0);
            #pragma unroll
            for (int kw = 0; kw < 3; ++kw) {
                int iw = 2 * ow + kw - 1;
                bool ok = vkh && (iw >= 0);
                int iwc = iw < 0 ? 0 : iw;
                const u32* xp = &xs[(kh * WW + iwc) * 8 + 4 * h];
                int p = 0;
                #pragma unroll
                for (int j = 0; j < 4; ++j) p += __popc(xp[j] ^ wreg[(kh * 3 + kw) * 4 + j]);
                Q += ok ? p : 0;
            }
        }
        qh[ow][h][c] = (ushort)Q;
    }
    __syncthreads();
    if (h == 0) {
        int rv = oh0 ? 2 : 3;
        int bsum = 0; long long bsq = 0;
        short* outp = S1 + ((size_t)(n * OHH + oh) * OWW) * CC + c;
        #pragma unroll
        for (int ow = 0; ow < OWW; ++ow) {
            int V = rv * (ow == 0 ? 2 : 3);
            int S = 256 * V - 2 * ((int)qh[ow][0][c] + (int)qh[ow][1][c]);
            outp[ow * CC] = (short)S;
            bsum += S;
            bsq += (long long)S * S;
        }
        atomicAdd(&s_sum[c], bsum);
        atomicAdd(&s_sq[c], (u64)bsq);
    }
}

// ---- BN finalize (exact integer stats -> A,B), inlined into consumers ----
__device__ __forceinline__ void bn_fold(const int* ssum, const u64* ssq,
                                        const float* alpha, const float* gamma,
                                        const float* beta, int c, float& a, float& b) {
    const double N = (double)NPIX;
    double s = (double)ssum[c];
    double q = (double)ssq[c];
    double mS = s / N;
    double vS = q / N - mS * mS;
    double al = (double)alpha[c];
    double scale = (double)gamma[c] / sqrt(al * al * vS + 1e-5);
    a = (float)(al * scale);
    b = (float)((double)beta[c] - al * mS * scale);
}

// ---------------- Kernel 3: out1 = rprelu(bn1+pool) (in-place) + conv2 bn2-stats ----------
// Block = (n, oh, ow-half of 14). Phase A: out1 + sign2 ballots to LDS. Phase B: 1x1
// binary conv from LDS bits -> stats only (S2 recomputed in rrb_final).
__global__ __launch_bounds__(256) void rrb_out1c2(const short* __restrict__ S1,
                                                  float* __restrict__ pool,
                                                  const int* __restrict__ ssum, const u64* __restrict__ ssq,
                                                  const float* __restrict__ alpha1,
                                                  const float* __restrict__ bn1g, const float* __restrict__ bn1b,
                                                  const float* __restrict__ pg, const float* __restrict__ pz,
                                                  const float* __restrict__ ps, const float* __restrict__ rsb2,
                                                  const u32* __restrict__ wp2,
                                                  int* __restrict__ s_sum2, u64* __restrict__ s_sq2) {
    __shared__ u32 xsb[14 * 8];      // 448 B of sign bits
    int blk = blockIdx.x;
    int half = blk & 1;
    int rest = blk >> 1;
    int n = rest / OHH, oh = rest - n * OHH;
    int owlo = half * 14;
    int c = threadIdx.x;
    int wid = c >> 6, lane = c & 63;
    float a, b;
    bn_fold(ssum, ssq, alpha1, bn1g, bn1b, c, a, b);
    float g = pg[c], z = pz[c], s = ps[c], b2 = rsb2[c];
    size_t pixbase = ((size_t)(n * OHH + oh) * OWW + owlo);
    const short* sp = S1 + pixbase * CC + c;
    float* pp = pool + pixbase * CC + c;
    float sv[14], pv[14];
    #pragma unroll
    for (int k = 0; k < 14; ++k) sv[k] = (float)sp[k * CC];
    #pragma unroll
    for (int k = 0; k < 14; ++k) pv[k] = pp[k * CC];
    #pragma unroll
    for (int k = 0; k < 14; ++k) {
        float v = a * sv[k] + b + pv[k];
        float xsv = v - g;
        float o = (xsv > 0.f ? xsv : s * xsv) + z;
        pp[k * CC] = o;
        u64 m = __ballot(o + b2 > 0.f);
        if (lane == 0) *(u64*)&xsb[k * 8 + 2 * wid] = m;
    }
    __syncthreads();
    u32 wr[8];
    {
        const u32* wsv = wp2 + (size_t)c * 8;
        #pragma unroll
        for (int j = 0; j < 8; ++j) wr[j] = wsv[j];
    }
    int bsum = 0; long long bsq = 0;
    #pragma unroll
    for (int k = 0; k < 14; ++k) {
        int p = 0;
        #pragma unroll
        for (int j = 0; j < 8; ++j) p += __popc(xsb[k * 8 + j] ^ wr[j]);
        int S = 256 - 2 * p;
        bsum += S;
        bsq += (long long)S * S;
    }
    atomicAdd(&s_sum2[c], bsum);
    atomicAdd(&s_sq2[c], (u64)bsq);
}

// ---------------- Kernel 4: recompute conv2 from out1, y = bn2 + out1, concat ----------
// Block (n, oh). Re-ballots the SAME sign bits as kernel 3 (same f32 -> bit-identical).
__global__ __launch_bounds__(256) void rrb_final(const float* __restrict__ out1,
                                                 const int* __restrict__ ssum, const u64* __restrict__ ssq,
                                                 const float* __restrict__ alpha2,
                                                 const float* __restrict__ bn2g, const float* __restrict__ bn2b,
                                                 const float* __restrict__ rsb2,
                                                 const u32* __restrict__ wp2,
                                                 float* __restrict__ y) {
    __shared__ u32 bits[OWW * 8];    // 896 B
    __shared__ float lds[256 * 29];  // 29.7 KB transpose buffer (pad 29)
    int blk = blockIdx.x;
    int n = blk / OHH, oh = blk - n * OHH;
    int c = threadIdx.x;
    int wid = c >> 6, lane = c & 63;
    float a, b;
    bn_fold(ssum, ssq, alpha2, bn2g, bn2b, c, a, b);
    float b2 = rsb2[c];
    size_t pixbase = ((size_t)(n * OHH + oh) * OWW);
    const float* op = out1 + pixbase * CC + c;
    float ov[OWW];
    #pragma unroll
    for (int ow = 0; ow < OWW; ++ow) ov[ow] = op[ow * CC];
    #pragma unroll
    for (int ow = 0; ow < OWW; ++ow) {
        u64 m = __ballot(ov[ow] + b2 > 0.f);
        if (lane == 0) *(u64*)&bits[ow * 8 + 2 * wid] = m;
    }
    u32 wr[8];
    {
        const u32* wsv = wp2 + (size_t)c * 8;
        #pragma unroll
        for (int j = 0; j < 8; ++j) wr[j] = wsv[j];
    }
    __syncthreads();
    #pragma unroll
    for (int ow = 0; ow < OWW; ++ow) {
        int p = 0;
        #pragma unroll
        for (int j = 0; j < 8; ++j) p += __popc(bits[ow * 8 + j] ^ wr[j]);
        int S = 256 - 2 * p;
        lds[c * 29 + ow] = a * (float)S + b + ov[ow];
    }
    __syncthreads();
    #pragma unroll
    for (int it = 0; it < 7; ++it) {
        int idx = it * 256 + c;        // 0..1791 = 256 rows x 7 float4
        int cp = idx / 7, qq = idx - cp * 7;
        const float* lp = &lds[cp * 29 + 4 * qq];
        float4 v = make_float4(lp[0], lp[1], lp[2], lp[3]);
        float* dst = y + ((size_t)(n * 2 * CC + cp) * OHH + oh) * OWW + 4 * qq;
        *(float4*)dst = v;
        *(float4*)(dst + (size_t)CC * OHH * OWW) = v;
    }
}

extern "C" void kernel_launch(void* const* d_in, const int* in_sizes, int n_in,
                              void* d_out, int out_size, void* d_ws, size_t ws_size,
                              hipStream_t stream) {
    const float* x    = (const float*)d_in[0];
    const float* rsb1 = (const float*)d_in[1];
    const float* w1   = (const float*)d_in[2];
    const float* bn1g = (const float*)d_in[3];
    const float* bn1b = (const float*)d_in[4];
    const float* rsb2 = (const float*)d_in[5];
    const float* w2   = (const float*)d_in[6];
    const float* bn2g = (const float*)d_in[7];
    const float* bn2b = (const float*)d_in[8];
    const float* pg   = (const float*)d_in[9];
    const float* pz   = (const float*)d_in[10];
    const float* ps   = (const float*)d_in[11];
    float* y = (float*)d_out;

    char* ws = (char*)d_ws;
    if (ws_size < 41840640) return;

    u32*   wp1    = (u32*)(ws + 0);          // 73728 B
    u32*   wp2    = (u32*)(ws + 73728);      // 8192 B
    float* alpha1 = (float*)(ws + 81920);
    float* alpha2 = (float*)(ws + 82944);
    int*   st1_sum = (int*)(ws + 88064);     // 1024 B
    u64*   st1_sq  = (u64*)(ws + 89088);     // 2048 B
    int*   st2_sum = (int*)(ws + 91136);     // 1024 B
    u64*   st2_sq  = (u64*)(ws + 92160);     // 2048 B  (stats: 6144 B @88064)
    u32*   xb   = (u32*)(ws + 94208);        // 3,211,264 B   [n][h][w][8]
    float* pool = (float*)(ws + 3305472);    // 25,690,112 B  [pix][256] (becomes out1)
    short* S1   = (short*)(ws + 28995584);   // 12,845,056 B  [pix][256] -> end 41,840,640

    rrb_prep_w<<<512, 256, 0, stream>>>(w1, w2, wp1, wp2, alpha1, alpha2,
                                        (u32*)(ws + 88064));
    rrb_pack_x<<<(BB * OHH * OWW * 8 * 4) / 256, 256, 0, stream>>>(x, rsb1, xb, pool);
    rrb_conv1<<<BB * OHH, 512, 0, stream>>>(xb, wp1, S1, st1_sum, st1_sq);
    rrb_out1c2<<<BB * OHH * 2, 256, 0, stream>>>(S1, pool, st1_sum, st1_sq, alpha1,
                                                 bn1g, bn1b, pg, pz, ps, rsb2,
                                                 wp2, st2_sum, st2_sq);
    rrb_final<<<BB * OHH, 256, 0, stream>>>(pool, st2_sum, st2_sq, alpha2,
                                            bn2g, bn2b, rsb2, wp2, y);
}